// Round 5
// baseline (1152.030 us; speedup 1.0000x reference)
//
#include <hip/hip_runtime.h>
#include <hip/hip_bf16.h>
#include <stdint.h>

#define BS 2
#define SL 2048
#define H 32
#define DH 128
#define ATT_ELEMS (BS*SL*H*DH)      /* 16777216 attn-output floats */
#define KTILES (SL/64)              /* 32 */
/* 1/sqrt(128) * log2(e): softmax carried in exp2 domain */
#define QSCALE (0.08838834764831845f * 1.4426950408889634f)

typedef __attribute__((ext_vector_type(8))) short short8_t;
typedef __attribute__((ext_vector_type(16))) float f32x16_t;
typedef __attribute__((ext_vector_type(4))) unsigned int u32x4_t;
typedef __attribute__((ext_vector_type(2))) unsigned int u32x2_t;

union FragU { u32x4_t u; short8_t s; };

__device__ __forceinline__ unsigned short f2bf(float x){
    union { float f; unsigned int u; } v; v.f = x;
    unsigned int r = v.u + 0x7fffu + ((v.u >> 16) & 1u);   // RNE
    return (unsigned short)(r >> 16);
}
__device__ __forceinline__ unsigned int pack2(float a, float b){
    return (unsigned int)f2bf(a) | ((unsigned int)f2bf(b) << 16);
}
__device__ __forceinline__ unsigned int cvtpk(float a, float b){
    unsigned int r;
    asm("v_cvt_pk_bf16_f32 %0, %1, %2" : "=v"(r) : "v"(a), "v"(b));
    return r;
}
__device__ __forceinline__ void gload16(const unsigned short* g, unsigned short* l){
    __builtin_amdgcn_global_load_lds(
        (const __attribute__((address_space(1))) void*)(const void*)g,
        (__attribute__((address_space(3))) void*)(void*)l, 16, 0, 0);
}

/* ---------------- prep: K,V fp32 -> bf16 in exact 32x32x16-MFMA fragment order ------------------
 * kfrag (per b,h,tile; 8192 shorts): chunk c (8 shorts), fi=c>>6, l=c&63:
 *   K[key = (fi>>3)*32 + (l&31)][d = (fi&7)*16 + (l>>5)*8 + 0..7]      (A-operand, QK)
 * vfrag: chunk c, fi=c>>6 (= dblk*4+ks), l=c&63:
 *   V[key = (fi&3)*16 + (l>>5)*8 + 0..7][d = (fi>>2)*32 + (l&31)]      (B-operand, PV)
 * Optionally also writes the paged cache output (fused path).                                     */
__global__ __launch_bounds__(256) void prep_kv_kernel(const float* __restrict__ xk,
                                                      const float* __restrict__ xv,
                                                      const int* __restrict__ pids,
                                                      unsigned short* __restrict__ kfr,
                                                      unsigned short* __restrict__ vfr,
                                                      float* __restrict__ out_cache,
                                                      int do_cache){
    __shared__ unsigned short tK[64*136];         // [key 64][d 128 + pad8]
    __shared__ unsigned short tV[64*136];
    int tile = blockIdx.x, h = blockIdx.y, b = blockIdx.z;
    int tid = threadIdx.x;
    size_t tbase = ((size_t)((b*H + h)*KTILES + tile)) * 8192;
    int pg[4];
    #pragma unroll
    for (int j = 0; j < 4; ++j) pg[j] = pids[b*128 + tile*4 + j];

    #pragma unroll
    for (int i = 0; i < 8; ++i){
        int c = tid + 256*i;
        int row = c >> 5, f4 = c & 31;
        size_t gidx = ((size_t)((b*SL + tile*64 + row)*H + h))*DH + f4*4;
        float4 kx = *(const float4*)(xk + gidx);
        float4 vx = *(const float4*)(xv + gidx);
        u32x2_t kw; kw[0] = pack2(kx.x, kx.y); kw[1] = pack2(kx.z, kx.w);
        u32x2_t vw; vw[0] = pack2(vx.x, vx.y); vw[1] = pack2(vx.z, vx.w);
        *(u32x2_t*)(&tK[row*136 + f4*4]) = kw;
        *(u32x2_t*)(&tV[row*136 + f4*4]) = vw;
        if (do_cache){
            size_t cb = (size_t)pg[row>>4]*131072 + (size_t)(row&15)*4096 + h*128 + f4*4;
            *(float4*)(out_cache + cb)         = kx;   // k partition
            *(float4*)(out_cache + cb + 65536) = vx;   // v partition
        }
    }
    __syncthreads();
    #pragma unroll
    for (int i = 0; i < 4; ++i){                  // K A-fragments
        int c = tid + 256*i;
        int fi = c >> 6, l = c & 63;
        int key = (fi >> 3)*32 + (l & 31);
        int d0  = (fi & 7)*16 + (l >> 5)*8;
        u32x4_t w = *(const u32x4_t*)(&tK[key*136 + d0]);
        *(u32x4_t*)(&kfr[tbase + (size_t)c*8]) = w;
    }
    #pragma unroll
    for (int i = 0; i < 4; ++i){                  // V B-fragments
        int c = tid + 256*i;
        int fi = c >> 6, l = c & 63;
        int d  = (fi >> 2)*32 + (l & 31);
        int k0 = (fi & 3)*16 + (l >> 5)*8;
        u32x4_t u;
        #pragma unroll
        for (int w = 0; w < 4; ++w)
            u[w] = (unsigned)tV[(k0+2*w)*136 + d] | ((unsigned)tV[(k0+2*w+1)*136 + d] << 16);
        *(u32x4_t*)(&vfr[tbase + (size_t)c*8]) = u;
    }
}

/* ---------------- fallback paged cache scatter (when frag scratch lives in cache region) ------- */
__global__ __launch_bounds__(256) void cache_scatter_kernel(const float* __restrict__ xk,
                                                            const float* __restrict__ xv,
                                                            const int* __restrict__ pids,
                                                            float* __restrict__ out_cache){
    int sb = blockIdx.x >> 1, part = blockIdx.x & 1;
    int page = pids[sb];
    const float4* s4 = (const float4*)((part ? xv : xk) + (size_t)sb * 65536);
    float4* d4 = (float4*)(out_cache + (size_t)page * 131072 + (size_t)part * 65536);
    int base = blockIdx.y * 2048 + threadIdx.x;
    #pragma unroll
    for (int i = 0; i < 8; ++i) d4[base + i*256] = s4[base + i*256];
}

/* ---------------- flash attention: 32x32x16 MFMA, block-shared V double-buffer -----------------
 * 4 waves/block share (b,h); each wave owns 32 q-rows. V tile is staged ONCE per block
 * (each wave DMAs 4 of 16 chunks) into a 2x16KB LDS double-buffer -> 32KB/block -> 4 blocks/CU.
 * K fragments stream global->regs per wave (compiler-tracked waits; V DMAs are always older
 * than the K loads, so the QK auto-wait drains each wave's own V DMA -> barrier A publishes).   */
__global__ __launch_bounds__(256, 4) void attn_kernel(const float* __restrict__ xq,
                                                      const unsigned short* __restrict__ kfr,
                                                      const unsigned short* __restrict__ vfr,
                                                      float* __restrict__ out){
    __shared__ unsigned short smem[2*8192];       // shared V double-buffer (32KB)

    const int tid  = threadIdx.x;
    const int lane = tid & 63;
    const int wave = tid >> 6;
    const int l31  = lane & 31;
    const int hi   = lane >> 5;

    int lin = blockIdx.x;                  // 0..1023
    int swz = (lin & 7)*128 + (lin >> 3);  // XCD-aware, bijective (1024 % 8 == 0)
    const int qblk = swz & 15;
    const int h    = (swz >> 4) & 31;
    const int b    = swz >> 9;
    const int qbase = qblk*128 + wave*32;

    // Q as MFMA B-operand fragments (scale folded with log2e)
    short8_t qf[8];
    {
        const float* qptr = xq + ((size_t)((b*SL + qbase + l31)*H + h))*DH + hi*8;
        #pragma unroll
        for (int f = 0; f < 8; ++f){
            float4 a = *(const float4*)(qptr + f*16);
            float4 c = *(const float4*)(qptr + f*16 + 4);
            FragU w;
            w.u[0] = pack2(a.x*QSCALE, a.y*QSCALE);
            w.u[1] = pack2(a.z*QSCALE, a.w*QSCALE);
            w.u[2] = pack2(c.x*QSCALE, c.y*QSCALE);
            w.u[3] = pack2(c.z*QSCALE, c.w*QSCALE);
            qf[f] = w.s;
        }
    }

    f32x16_t acc[4];
    #pragma unroll
    for (int d = 0; d < 4; ++d)
        #pragma unroll
        for (int r = 0; r < 16; ++r) acc[d][r] = 0.f;
    float m = -1e30f, l_run = 0.f;

    const size_t bh = (size_t)(b*H + h) * (KTILES*8192);
    const unsigned short* kg = kfr + bh;
    const unsigned short* vg = vfr + bh;

    // prologue: stage V(0) chunks (this wave's 4 of 16) BEFORE K(0) loads -> V older than K
    #pragma unroll
    for (int i = 0; i < 4; ++i){
        int ch = wave*4 + i;
        gload16(vg + ch*512 + lane*8, smem + ch*512);
    }
    __builtin_amdgcn_sched_barrier(0);

    FragU kreg[16];
    #pragma unroll
    for (int i = 0; i < 16; ++i)
        kreg[i].u = *(const u32x4_t*)(kg + i*512 + lane*8);

    #pragma unroll 1
    for (int t = 0; t < KTILES; ++t){
        const int p = t & 1;
        unsigned short* Vc = smem + p*8192;

        // ---- stage V(t+1) into buf[p^1]: 4 chunks per wave (barrier B of tile t-1 cleared it) --
        if (t + 1 < KTILES){
            const unsigned short* vt = vg + (size_t)(t+1)*8192;
            unsigned short* Vn = smem + (p^1)*8192;
            #pragma unroll
            for (int i = 0; i < 4; ++i){
                int ch = wave*4 + i;
                gload16(vt + ch*512 + lane*8, Vn + ch*512);
            }
        }
        __builtin_amdgcn_sched_barrier(0);   // pin: V DMA issues before QK

        // ---- QK: S^T = K x Q (compiler auto-waits kreg loads; drains older V(t) DMA too) ----
        f32x16_t s0, s1;
        #pragma unroll
        for (int r = 0; r < 16; ++r){ s0[r] = 0.f; s1[r] = 0.f; }
        __builtin_amdgcn_s_setprio(1);
        #pragma unroll
        for (int f = 0; f < 8; ++f){
            s0 = __builtin_amdgcn_mfma_f32_32x32x16_bf16(kreg[f].s,   qf[f], s0, 0, 0, 0);
            s1 = __builtin_amdgcn_mfma_f32_32x32x16_bf16(kreg[8+f].s, qf[f], s1, 0, 0, 0);
        }
        __builtin_amdgcn_s_setprio(0);
        __builtin_amdgcn_sched_barrier(0);   // pin: K(t+1) loads stay below QK

        // ---- prefetch K(t+1) fragments into registers (hidden under softmax+PV) ----
        if (t + 1 < KTILES){
            const unsigned short* kn = kg + (size_t)(t+1)*8192;
            #pragma unroll
            for (int i = 0; i < 16; ++i)
                kreg[i].u = *(const u32x4_t*)(kn + i*512 + lane*8);
        }
        __builtin_amdgcn_sched_barrier(0);   // pin: K(t+1) loads issue before softmax

        // ---- online softmax (exp2 domain, defer-max THR=8), tree-reduced max ----
        float t16[16];
        #pragma unroll
        for (int r = 0; r < 16; ++r) t16[r] = fmaxf(s0[r], s1[r]);
        #pragma unroll
        for (int w = 8; w >= 1; w >>= 1)
            #pragma unroll
            for (int r = 0; r < 8; ++r)
                if (r < w) t16[r] = fmaxf(t16[r], t16[r+w]);
        float tmax = fmaxf(t16[0], __shfl_xor(t16[0], 32, 64));

        if (!__all(tmax - m <= 8.f)){
            float mn = fmaxf(m, tmax);
            float corr = __builtin_amdgcn_exp2f(m - mn);
            l_run *= corr;
            float cr[16];
            #pragma unroll
            for (int r = 0; r < 16; ++r)
                cr[r] = __shfl(corr, (r&3) + 8*(r>>2) + 4*hi, 64);
            #pragma unroll
            for (int d = 0; d < 4; ++d)
                #pragma unroll
                for (int r = 0; r < 16; ++r) acc[d][r] *= cr[r];
            m = mn;
        }

        float lsum = 0.f;
        FragU pf[4];
        // slice ks covers keys ks*16..ks*16+15; p-values s{kb}[rbase..rbase+7]
        #define PSLICE(KS, SV, RB)                                                          \
        {                                                                                   \
            float e0 = __builtin_amdgcn_exp2f(SV[RB+0] - m);                                \
            float e1 = __builtin_amdgcn_exp2f(SV[RB+1] - m);                                \
            float e2 = __builtin_amdgcn_exp2f(SV[RB+2] - m);                                \
            float e3 = __builtin_amdgcn_exp2f(SV[RB+3] - m);                                \
            float e4 = __builtin_amdgcn_exp2f(SV[RB+4] - m);                                \
            float e5 = __builtin_amdgcn_exp2f(SV[RB+5] - m);                                \
            float e6 = __builtin_amdgcn_exp2f(SV[RB+6] - m);                                \
            float e7 = __builtin_amdgcn_exp2f(SV[RB+7] - m);                                \
            lsum += ((e0+e1)+(e2+e3)) + ((e4+e5)+(e6+e7));                                  \
            unsigned a  = cvtpk(e0,e1), bq = cvtpk(e2,e3);                                  \
            unsigned cq = cvtpk(e4,e5), dq = cvtpk(e6,e7);                                  \
            unsigned y0 = hi ? a : cq,  y1 = hi ? bq : dq;                                  \
            unsigned r0 = __shfl_xor(y0, 32, 64);                                           \
            unsigned r1 = __shfl_xor(y1, 32, 64);                                           \
            pf[KS].u[0] = hi ? r0 : a;  pf[KS].u[1] = hi ? r1 : bq;                         \
            pf[KS].u[2] = hi ? cq : r0; pf[KS].u[3] = hi ? dq : r1;                         \
        }
        PSLICE(0, s0, 0)
        PSLICE(1, s0, 8)
        PSLICE(2, s1, 0)
        PSLICE(3, s1, 8)
        #undef PSLICE
        lsum += __shfl_xor(lsum, 32, 64);
        l_run += lsum;

        // ---- barrier A: all waves' V(t) DMA drained (each via its own QK auto-wait) ----
        asm volatile("s_waitcnt vmcnt(20)" ::: "memory");  // no-op insurance: V(t+1)4+K(t+1)16
        __builtin_amdgcn_s_barrier();
        __builtin_amdgcn_sched_barrier(0);

        // ---- PV from shared buf[p] ----
        __builtin_amdgcn_s_setprio(1);
        #pragma unroll
        for (int dblk = 0; dblk < 4; ++dblk){
            #pragma unroll
            for (int ks = 0; ks < 4; ++ks){
                FragU vb;
                vb.u = *(const u32x4_t*)(&Vc[(dblk*4 + ks)*512 + lane*8]);
                acc[dblk] = __builtin_amdgcn_mfma_f32_32x32x16_bf16(pf[ks].s, vb.s, acc[dblk], 0, 0, 0);
            }
        }
        __builtin_amdgcn_s_setprio(0);
        __builtin_amdgcn_sched_barrier(0);

        // ---- barrier B: all waves done reading buf[p]; next iter's stage overwrites it ----
        if (t + 1 < KTILES) __builtin_amdgcn_s_barrier();
    }

    // ---- epilogue: divide by softmax denominator, store ----
    float linv = 1.f / l_run;
    float lr[16];
    #pragma unroll
    for (int r = 0; r < 16; ++r)
        lr[r] = __shfl(linv, (r&3) + 8*(r>>2) + 4*hi, 64);
    #pragma unroll
    for (int dblk = 0; dblk < 4; ++dblk){
        #pragma unroll
        for (int r = 0; r < 16; ++r){
            int q = qbase + (r&3) + 8*(r>>2) + 4*hi;
            out[(size_t)(b*SL + q)*(H*DH) + h*DH + dblk*32 + l31] = acc[dblk][r] * lr[r];
        }
    }
}

extern "C" void kernel_launch(void* const* d_in, const int* in_sizes, int n_in,
                              void* d_out, int out_size, void* d_ws, size_t ws_size,
                              hipStream_t stream) {
    const float* xq = (const float*)d_in[0];
    const float* xk = (const float*)d_in[1];
    const float* xv = (const float*)d_in[2];
    /* d_in[3] = cache_state: unused — seq_block_ids covers all 256 pages, so the
       cache writes below overwrite every element of the cache output. */
    const int* pids = (const int*)d_in[4];

    float* out_attn  = (float*)d_out;
    float* out_cache = out_attn + (size_t)ATT_ELEMS;

    const size_t frag_elems = (size_t)BS*H*KTILES*8192;           /* shorts per tensor */
    const size_t need       = 2*frag_elems*sizeof(unsigned short); /* 67 MB */

    if (ws_size >= need){
        /* fused path: frag scratch in d_ws; prep reads xk/xv ONCE and also writes the cache */
        unsigned short* kfr = (unsigned short*)d_ws;
        unsigned short* vfr = kfr + frag_elems;
        prep_kv_kernel<<<dim3(KTILES, H, BS), 256, 0, stream>>>(xk, xv, pids, kfr, vfr, out_cache, 1);
        attn_kernel<<<dim3(BS*H*(SL/128)), 256, 0, stream>>>(xq, kfr, vfr, out_attn);
    } else {
        /* fallback: frag scratch lives in the cache output region (fully overwritten later) */
        unsigned short* vfr = (unsigned short*)out_cache;
        unsigned short* kfr = vfr + frag_elems;
        prep_kv_kernel<<<dim3(KTILES, H, BS), 256, 0, stream>>>(xk, xv, pids, kfr, vfr, out_cache, 0);
        attn_kernel<<<dim3(BS*H*(SL/128)), 256, 0, stream>>>(xq, kfr, vfr, out_attn);
        cache_scatter_kernel<<<dim3(512, 8), 256, 0, stream>>>(xk, xv, pids, out_cache);
    }
}

// Round 6
// 236.507 us; speedup vs baseline: 4.8710x; 4.8710x over previous
//
#include <hip/hip_runtime.h>
#include <hip/hip_bf16.h>
#include <stdint.h>

#define BS 2
#define SL 2048
#define H 32
#define DH 128
#define ATT_ELEMS (BS*SL*H*DH)      /* 16777216 attn-output floats */
#define KTILES (SL/64)              /* 32 */
/* 1/sqrt(128) * log2(e): softmax carried in exp2 domain */
#define QSCALE (0.08838834764831845f * 1.4426950408889634f)

typedef __attribute__((ext_vector_type(8))) short short8_t;
typedef __attribute__((ext_vector_type(16))) float f32x16_t;
typedef __attribute__((ext_vector_type(4))) unsigned int u32x4_t;
typedef __attribute__((ext_vector_type(2))) unsigned int u32x2_t;

union FragU { u32x4_t u; short8_t s; };

__device__ __forceinline__ unsigned short f2bf(float x){
    union { float f; unsigned int u; } v; v.f = x;
    unsigned int r = v.u + 0x7fffu + ((v.u >> 16) & 1u);   // RNE
    return (unsigned short)(r >> 16);
}
__device__ __forceinline__ unsigned int pack2(float a, float b){
    return (unsigned int)f2bf(a) | ((unsigned int)f2bf(b) << 16);
}
__device__ __forceinline__ unsigned int cvtpk(float a, float b){
    unsigned int r;
    asm("v_cvt_pk_bf16_f32 %0, %1, %2" : "=v"(r) : "v"(a), "v"(b));
    return r;
}
__device__ __forceinline__ void gload16(const unsigned short* g, unsigned short* l){
    __builtin_amdgcn_global_load_lds(
        (const __attribute__((address_space(1))) void*)(const void*)g,
        (__attribute__((address_space(3))) void*)(void*)l, 16, 0, 0);
}

/* ---------------- prep: K,V fp32 -> bf16 in exact 32x32x16-MFMA fragment order ------------------
 * kfrag (per b,h,tile; 8192 shorts): chunk c (8 shorts), fi=c>>6, l=c&63:
 *   K[key = (fi>>3)*32 + (l&31)][d = (fi&7)*16 + (l>>5)*8 + 0..7]      (A-operand, QK)
 * vfrag: chunk c, fi=c>>6 (= dblk*4+ks), l=c&63:
 *   V[key = (fi&3)*16 + (l>>5)*8 + 0..7][d = (fi>>2)*32 + (l&31)]      (B-operand, PV)
 * Optionally also writes the paged cache output (fused path).                                     */
__global__ __launch_bounds__(256) void prep_kv_kernel(const float* __restrict__ xk,
                                                      const float* __restrict__ xv,
                                                      const int* __restrict__ pids,
                                                      unsigned short* __restrict__ kfr,
                                                      unsigned short* __restrict__ vfr,
                                                      float* __restrict__ out_cache,
                                                      int do_cache){
    __shared__ unsigned short tK[64*136];         // [key 64][d 128 + pad8]
    __shared__ unsigned short tV[64*136];
    int tile = blockIdx.x, h = blockIdx.y, b = blockIdx.z;
    int tid = threadIdx.x;
    size_t tbase = ((size_t)((b*H + h)*KTILES + tile)) * 8192;
    int pg[4];
    #pragma unroll
    for (int j = 0; j < 4; ++j) pg[j] = pids[b*128 + tile*4 + j];

    #pragma unroll
    for (int i = 0; i < 8; ++i){
        int c = tid + 256*i;
        int row = c >> 5, f4 = c & 31;
        size_t gidx = ((size_t)((b*SL + tile*64 + row)*H + h))*DH + f4*4;
        float4 kx = *(const float4*)(xk + gidx);
        float4 vx = *(const float4*)(xv + gidx);
        u32x2_t kw; kw[0] = pack2(kx.x, kx.y); kw[1] = pack2(kx.z, kx.w);
        u32x2_t vw; vw[0] = pack2(vx.x, vx.y); vw[1] = pack2(vx.z, vx.w);
        *(u32x2_t*)(&tK[row*136 + f4*4]) = kw;
        *(u32x2_t*)(&tV[row*136 + f4*4]) = vw;
        if (do_cache){
            size_t cb = (size_t)pg[row>>4]*131072 + (size_t)(row&15)*4096 + h*128 + f4*4;
            *(float4*)(out_cache + cb)         = kx;   // k partition
            *(float4*)(out_cache + cb + 65536) = vx;   // v partition
        }
    }
    __syncthreads();
    #pragma unroll
    for (int i = 0; i < 4; ++i){                  // K A-fragments
        int c = tid + 256*i;
        int fi = c >> 6, l = c & 63;
        int key = (fi >> 3)*32 + (l & 31);
        int d0  = (fi & 7)*16 + (l >> 5)*8;
        u32x4_t w = *(const u32x4_t*)(&tK[key*136 + d0]);
        *(u32x4_t*)(&kfr[tbase + (size_t)c*8]) = w;
    }
    #pragma unroll
    for (int i = 0; i < 4; ++i){                  // V B-fragments
        int c = tid + 256*i;
        int fi = c >> 6, l = c & 63;
        int d  = (fi >> 2)*32 + (l & 31);
        int k0 = (fi & 3)*16 + (l >> 5)*8;
        u32x4_t u;
        #pragma unroll
        for (int w = 0; w < 4; ++w)
            u[w] = (unsigned)tV[(k0+2*w)*136 + d] | ((unsigned)tV[(k0+2*w+1)*136 + d] << 16);
        *(u32x4_t*)(&vfr[tbase + (size_t)c*8]) = u;
    }
}

/* ---------------- fallback paged cache scatter (when frag scratch lives in cache region) ------- */
__global__ __launch_bounds__(256) void cache_scatter_kernel(const float* __restrict__ xk,
                                                            const float* __restrict__ xv,
                                                            const int* __restrict__ pids,
                                                            float* __restrict__ out_cache){
    int sb = blockIdx.x >> 1, part = blockIdx.x & 1;
    int page = pids[sb];
    const float4* s4 = (const float4*)((part ? xv : xk) + (size_t)sb * 65536);
    float4* d4 = (float4*)(out_cache + (size_t)page * 131072 + (size_t)part * 65536);
    int base = blockIdx.y * 2048 + threadIdx.x;
    #pragma unroll
    for (int i = 0; i < 8; ++i) d4[base + i*256] = s4[base + i*256];
}

/* ---------------- flash attention: 32x32x16 MFMA, shared K+V LDS double-buffer, 1 barrier/tile -
 * 4 waves/block share (b,h); each wave owns 32 q-rows. K(t+1),V(t+1) are DMA'd (4+4 chunks per
 * wave) into the other half of a 4x16KB LDS buffer pool at the TOP of tile t and consumed at
 * tile t+1 -> every VMEM op has a full tile (~2-4k cyc) of latency cover. One vmcnt(0)+barrier
 * per tile publishes; no mid-tile VMEM waits. QK uses 4 independent MFMA chains.               */
__global__ __launch_bounds__(256, 2) void attn_kernel(const float* __restrict__ xq,
                                                      const unsigned short* __restrict__ kfr,
                                                      const unsigned short* __restrict__ vfr,
                                                      float* __restrict__ out){
    __shared__ unsigned short smem[4*8192];       // [K0|K1|V0|V1], 64KB

    const int tid  = threadIdx.x;
    const int lane = tid & 63;
    const int wave = tid >> 6;
    const int l31  = lane & 31;
    const int hi   = lane >> 5;

    int lin = blockIdx.x;                  // 0..1023
    int swz = (lin & 7)*128 + (lin >> 3);  // XCD-aware, bijective (1024 % 8 == 0)
    const int qblk = swz & 15;
    const int h    = (swz >> 4) & 31;
    const int b    = swz >> 9;
    const int qbase = qblk*128 + wave*32;

    // Q as MFMA B-operand fragments (scale folded with log2e)
    short8_t qf[8];
    {
        const float* qptr = xq + ((size_t)((b*SL + qbase + l31)*H + h))*DH + hi*8;
        #pragma unroll
        for (int f = 0; f < 8; ++f){
            float4 a = *(const float4*)(qptr + f*16);
            float4 c = *(const float4*)(qptr + f*16 + 4);
            FragU w;
            w.u[0] = pack2(a.x*QSCALE, a.y*QSCALE);
            w.u[1] = pack2(a.z*QSCALE, a.w*QSCALE);
            w.u[2] = pack2(c.x*QSCALE, c.y*QSCALE);
            w.u[3] = pack2(c.z*QSCALE, c.w*QSCALE);
            qf[f] = w.s;
        }
    }

    f32x16_t acc[4];
    #pragma unroll
    for (int d = 0; d < 4; ++d)
        #pragma unroll
        for (int r = 0; r < 16; ++r) acc[d][r] = 0.f;
    float m = -1e30f, l_run = 0.f;

    const size_t bh = (size_t)(b*H + h) * (KTILES*8192);
    const unsigned short* kg = kfr + bh;
    const unsigned short* vg = vfr + bh;

    // prologue: DMA K(0),V(0) into buffer half 0; publish
    #pragma unroll
    for (int i = 0; i < 4; ++i){
        int ch = wave*4 + i;
        gload16(kg + ch*512 + lane*8, smem + ch*512);
        gload16(vg + ch*512 + lane*8, smem + 16384 + ch*512);
    }
    asm volatile("s_waitcnt vmcnt(0)" ::: "memory");
    __builtin_amdgcn_s_barrier();
    asm volatile("" ::: "memory");

    #pragma unroll 1
    for (int t = 0; t < KTILES; ++t){
        const int p = t & 1;
        unsigned short* Kc = smem + p*8192;
        unsigned short* Vc = smem + 16384 + p*8192;

        // ---- issue DMAs for tile t+1 into the other half (free since entry barrier) ----
        if (t + 1 < KTILES){
            const unsigned short* kn = kg + (size_t)(t+1)*8192;
            const unsigned short* vn = vg + (size_t)(t+1)*8192;
            unsigned short* Kn = smem + (p^1)*8192;
            unsigned short* Vn = smem + 16384 + (p^1)*8192;
            #pragma unroll
            for (int i = 0; i < 4; ++i){
                int ch = wave*4 + i;
                gload16(kn + ch*512 + lane*8, Kn + ch*512);
                gload16(vn + ch*512 + lane*8, Vn + ch*512);
            }
        }
        __builtin_amdgcn_sched_barrier(0);   // pin: DMAs issue before compute

        // ---- QK: S^T = K x Q, 4 independent MFMA chains (covers MFMA latency) ----
        f32x16_t s0a, s0b, s1a, s1b;
        #pragma unroll
        for (int r = 0; r < 16; ++r){ s0a[r] = 0.f; s0b[r] = 0.f; s1a[r] = 0.f; s1b[r] = 0.f; }
        __builtin_amdgcn_s_setprio(1);
        #pragma unroll
        for (int f = 0; f < 4; ++f){
            FragU k0, k1, k2, k3;
            k0.u = *(const u32x4_t*)(&Kc[(f   )*512 + lane*8]);
            k1.u = *(const u32x4_t*)(&Kc[(8+f )*512 + lane*8]);
            k2.u = *(const u32x4_t*)(&Kc[(4+f )*512 + lane*8]);
            k3.u = *(const u32x4_t*)(&Kc[(12+f)*512 + lane*8]);
            s0a = __builtin_amdgcn_mfma_f32_32x32x16_bf16(k0.s, qf[f],   s0a, 0, 0, 0);
            s1a = __builtin_amdgcn_mfma_f32_32x32x16_bf16(k1.s, qf[f],   s1a, 0, 0, 0);
            s0b = __builtin_amdgcn_mfma_f32_32x32x16_bf16(k2.s, qf[4+f], s0b, 0, 0, 0);
            s1b = __builtin_amdgcn_mfma_f32_32x32x16_bf16(k3.s, qf[4+f], s1b, 0, 0, 0);
        }
        __builtin_amdgcn_s_setprio(0);
        f32x16_t s0 = s0a + s0b;
        f32x16_t s1 = s1a + s1b;

        // ---- online softmax (exp2 domain, defer-max THR=8), tree-reduced max ----
        float t16[16];
        #pragma unroll
        for (int r = 0; r < 16; ++r) t16[r] = fmaxf(s0[r], s1[r]);
        #pragma unroll
        for (int w = 8; w >= 1; w >>= 1)
            #pragma unroll
            for (int r = 0; r < 8; ++r)
                if (r < w) t16[r] = fmaxf(t16[r], t16[r+w]);
        float tmax = fmaxf(t16[0], __shfl_xor(t16[0], 32, 64));

        if (!__all(tmax - m <= 8.f)){
            float mn = fmaxf(m, tmax);
            float corr = __builtin_amdgcn_exp2f(m - mn);
            l_run *= corr;
            float cr[16];
            #pragma unroll
            for (int r = 0; r < 16; ++r)
                cr[r] = __shfl(corr, (r&3) + 8*(r>>2) + 4*hi, 64);
            #pragma unroll
            for (int d = 0; d < 4; ++d)
                #pragma unroll
                for (int r = 0; r < 16; ++r) acc[d][r] *= cr[r];
            m = mn;
        }

        float lsum = 0.f;
        FragU pf[4];
        // slice ks covers keys ks*16..ks*16+15; p-values s{kb}[rbase..rbase+7]
        #define PSLICE(KS, SV, RB)                                                          \
        {                                                                                   \
            float e0 = __builtin_amdgcn_exp2f(SV[RB+0] - m);                                \
            float e1 = __builtin_amdgcn_exp2f(SV[RB+1] - m);                                \
            float e2 = __builtin_amdgcn_exp2f(SV[RB+2] - m);                                \
            float e3 = __builtin_amdgcn_exp2f(SV[RB+3] - m);                                \
            float e4 = __builtin_amdgcn_exp2f(SV[RB+4] - m);                                \
            float e5 = __builtin_amdgcn_exp2f(SV[RB+5] - m);                                \
            float e6 = __builtin_amdgcn_exp2f(SV[RB+6] - m);                                \
            float e7 = __builtin_amdgcn_exp2f(SV[RB+7] - m);                                \
            lsum += ((e0+e1)+(e2+e3)) + ((e4+e5)+(e6+e7));                                  \
            unsigned a  = cvtpk(e0,e1), bq = cvtpk(e2,e3);                                  \
            unsigned cq = cvtpk(e4,e5), dq = cvtpk(e6,e7);                                  \
            unsigned y0 = hi ? a : cq,  y1 = hi ? bq : dq;                                  \
            unsigned r0 = __shfl_xor(y0, 32, 64);                                           \
            unsigned r1 = __shfl_xor(y1, 32, 64);                                           \
            pf[KS].u[0] = hi ? r0 : a;  pf[KS].u[1] = hi ? r1 : bq;                         \
            pf[KS].u[2] = hi ? cq : r0; pf[KS].u[3] = hi ? dq : r1;                         \
        }
        PSLICE(0, s0, 0)
        PSLICE(1, s0, 8)
        PSLICE(2, s1, 0)
        PSLICE(3, s1, 8)
        #undef PSLICE
        lsum += __shfl_xor(lsum, 32, 64);
        l_run += lsum;

        // ---- PV from Vc (published at entry barrier; no VMEM wait needed) ----
        __builtin_amdgcn_s_setprio(1);
        #pragma unroll
        for (int dblk = 0; dblk < 4; ++dblk){
            #pragma unroll
            for (int ks = 0; ks < 4; ++ks){
                FragU vb;
                vb.u = *(const u32x4_t*)(&Vc[(dblk*4 + ks)*512 + lane*8]);
                acc[dblk] = __builtin_amdgcn_mfma_f32_32x32x16_bf16(pf[ks].s, vb.s, acc[dblk], 0, 0, 0);
            }
        }
        __builtin_amdgcn_s_setprio(0);

        // ---- exit barrier: own DMAs (issued a full tile ago) drained, then publish ----
        if (t + 1 < KTILES){
            asm volatile("s_waitcnt vmcnt(0)" ::: "memory");
            __builtin_amdgcn_s_barrier();
            asm volatile("" ::: "memory");
        }
    }

    // ---- epilogue: divide by softmax denominator, store ----
    float linv = 1.f / l_run;
    float lr[16];
    #pragma unroll
    for (int r = 0; r < 16; ++r)
        lr[r] = __shfl(linv, (r&3) + 8*(r>>2) + 4*hi, 64);
    #pragma unroll
    for (int dblk = 0; dblk < 4; ++dblk){
        #pragma unroll
        for (int r = 0; r < 16; ++r){
            int q = qbase + (r&3) + 8*(r>>2) + 4*hi;
            out[(size_t)(b*SL + q)*(H*DH) + h*DH + dblk*32 + l31] = acc[dblk][r] * lr[r];
        }
    }
}

extern "C" void kernel_launch(void* const* d_in, const int* in_sizes, int n_in,
                              void* d_out, int out_size, void* d_ws, size_t ws_size,
                              hipStream_t stream) {
    const float* xq = (const float*)d_in[0];
    const float* xk = (const float*)d_in[1];
    const float* xv = (const float*)d_in[2];
    /* d_in[3] = cache_state: unused — seq_block_ids covers all 256 pages, so the
       cache writes below overwrite every element of the cache output. */
    const int* pids = (const int*)d_in[4];

    float* out_attn  = (float*)d_out;
    float* out_cache = out_attn + (size_t)ATT_ELEMS;

    const size_t frag_elems = (size_t)BS*H*KTILES*8192;           /* shorts per tensor */
    const size_t need       = 2*frag_elems*sizeof(unsigned short); /* 67 MB */

    if (ws_size >= need){
        /* fused path: frag scratch in d_ws; prep reads xk/xv ONCE and also writes the cache */
        unsigned short* kfr = (unsigned short*)d_ws;
        unsigned short* vfr = kfr + frag_elems;
        prep_kv_kernel<<<dim3(KTILES, H, BS), 256, 0, stream>>>(xk, xv, pids, kfr, vfr, out_cache, 1);
        attn_kernel<<<dim3(BS*H*(SL/128)), 256, 0, stream>>>(xq, kfr, vfr, out_attn);
    } else {
        /* fallback: frag scratch lives in the cache output region (fully overwritten later) */
        unsigned short* vfr = (unsigned short*)out_cache;
        unsigned short* kfr = vfr + frag_elems;
        prep_kv_kernel<<<dim3(KTILES, H, BS), 256, 0, stream>>>(xk, xv, pids, kfr, vfr, out_cache, 0);
        attn_kernel<<<dim3(BS*H*(SL/128)), 256, 0, stream>>>(xq, kfr, vfr, out_attn);
        cache_scatter_kernel<<<dim3(512, 8), 256, 0, stream>>>(xk, xv, pids, out_cache);
    }
}